// Round 6
// baseline (302.552 us; speedup 1.0000x reference)
//
#include <hip/hip_runtime.h>
#include <math.h>

#pragma clang fp contract(off)

#define HW      (2048*2048)
#define NI      4096        // instances per image
#define MAXPIX  1024        // pixels per instance (equal partition)
#define NF      200
#define FEAT    209
#define NE      (NI*2)
#define XSIZE   ((2*NI)*FEAT)
#define EIOFF   XSIZE
#define EAOFF   (EIOFF + 2*NE)

#define S       8192        // pixels per chunk (one sort block)
#define CHK     (HW/S)      // 512 chunks per image
#define TOTCHK  (2*CHK)     // 1024
#define NBPI    256         // buckets per image (16 labels each)
#define LPB     16
#define NBG     (2*NBPI)    // 512 global buckets
#define REC     (2*HW)
#define BTOT    (LPB*MAXPIX) // 16384 records per bucket (equal partition => static)
#define NWS     16          // waves per sort block
#define NXCD    8

template<int NB>
__device__ __forceinline__ unsigned long long match_bits(int v) {
    unsigned long long m = ~0ull;
    #pragma unroll
    for (int bit = 0; bit < NB; ++bit) {
        unsigned long long bb = __ballot((v >> bit) & 1);
        m &= ((v >> bit) & 1) ? bb : ~bb;
    }
    return m;
}

// ---- pass 1: per-chunk bucket counts + per-block per-label fz partials ---
__global__ void __launch_bounds__(512) count_zf_kernel(const int* __restrict__ mask1,
        const int* __restrict__ mask2, const float* __restrict__ flow1,
        const float* __restrict__ flow2, unsigned* __restrict__ cntA,
        float* __restrict__ zfpart) {
    __shared__ unsigned cnt[8][NBPI];    // 8 KB
    __shared__ float zfp[NI];            // 16 KB
    int t = threadIdx.x, w = t >> 6, lane = t & 63;
    for (int j = t; j < 8*NBPI; j += 512) ((unsigned*)cnt)[j] = 0u;
    for (int j = t; j < NI; j += 512) zfp[j] = 0.f;
    __syncthreads();
    int c = blockIdx.x;
    int img = c / CHK;
    const int4*   mask  = (const int4*)(img ? mask2 : mask1);
    const float4* flowz = (const float4*)((img ? flow2 : flow1) + 2L*HW);
    long base4 = (long)(c - img*CHK) * (S/4) + (long)w * (S/32);  // per-wave eighth
    #pragma unroll
    for (int it = 0; it < S/32; it += 64) {
        int4   l4 = mask[base4 + it + lane];
        float4 fz = flowz[base4 + it + lane];
        atomicAdd(&cnt[w][(l4.x-1) >> 4], 1u);
        atomicAdd(&cnt[w][(l4.y-1) >> 4], 1u);
        atomicAdd(&cnt[w][(l4.z-1) >> 4], 1u);
        atomicAdd(&cnt[w][(l4.w-1) >> 4], 1u);
        atomicAdd(&zfp[l4.x-1], fz.x);
        atomicAdd(&zfp[l4.y-1], fz.y);
        atomicAdd(&zfp[l4.z-1], fz.z);
        atomicAdd(&zfp[l4.w-1], fz.w);
    }
    __syncthreads();
    if (t < NBPI) {
        unsigned s = 0;
        #pragma unroll
        for (int q = 0; q < 8; ++q) s += cnt[q][t];
        cntA[(long)c * NBPI + t] = s;
    }
    float* zdst = zfpart + (long)c * NI;
    for (int j = t; j < NI; j += 512) zdst[j] = zfp[j];
}

// ---- pass 2 (merged): per-bucket chunk scan  +  zf partial reduction -----
__global__ void __launch_bounds__(1024) scan_zf_kernel(unsigned* __restrict__ cntA,
        const float* __restrict__ zfpart, float* __restrict__ zfm) {
    __shared__ float red[16][64];            // 4 KB (zfred) / wsum alias (scan)
    int* wsum = (int*)red;
    int b = blockIdx.x;
    int t = threadIdx.x, lane = t & 63, w = t >> 6;
    if (b < NBG) {
        // exclusive scan of cntA[.][lb] over the image's 512 chunks
        int img = b >> 8, lb = b & (NBPI - 1);
        unsigned e = 0;
        if (t < CHK) e = cntA[((long)img*CHK + t)*NBPI + lb];
        int incl = (int)e;
        #pragma unroll
        for (int off = 1; off < 64; off <<= 1) {
            int o = __shfl_up(incl, off);
            if (lane >= off) incl += o;
        }
        if (lane == 63) wsum[w] = incl;
        __syncthreads();
        if (t < CHK) {
            int add = 0;
            for (int q = 0; q < w; ++q) add += wsum[q];
            cntA[((long)img*CHK + t)*NBPI + lb] = (unsigned)(incl + add - (int)e);
        }
    } else {
        // zf reduction: 64 labels per block, fully coalesced 256B/wave loads
        int b2 = b - NBG;                    // 0..127
        int img = b2 >> 6;
        int l0  = (b2 & 63) * 64;
        int rg = t >> 6;
        const float* p = zfpart + ((long)img*CHK + rg)*NI + l0 + lane;
        float s = 0.f;
        #pragma unroll 8
        for (int r = 0; r < CHK; r += 16) s += p[(long)r*NI];
        red[rg][lane] = s;
        __syncthreads();
        if (t < 64) {
            float sum = 0.f;
            #pragma unroll
            for (int g = 0; g < 16; ++g) sum += red[g][t];
            zfm[img*NI + l0 + t] = sum * (1.0f/(float)MAXPIX);   // exact /1024
        }
    }
}

// ---- pass 3: LDS-staged stable bucket sort -------------------------------
// 1024 threads, 57344 B LDS => 2 blocks/CU. Vector loads + LDS redistribute:
// 8 wide independent loads/thread replace 32 scalar dependent loads.
__global__ void __launch_bounds__(1024, 8) sort_kernel(
        const float* __restrict__ img1, const float* __restrict__ img2,
        const float* __restrict__ flow1, const float* __restrict__ flow2,
        const int* __restrict__ mask1, const int* __restrict__ mask2,
        const unsigned* __restrict__ cntA,
        float* __restrict__ riv, unsigned char* __restrict__ rmeta) {
    __shared__ float ivs[S];                     // 32 KB (staging, then records)
    __shared__ unsigned short smeta[S];          // 16 KB (staging, then records)
    __shared__ unsigned short cw[NWS][NBPI];     // 8 KB   => 57344 B total
    int* wsum  = (int*)smeta;                    // alias: staged metas consumed first
    int* gofsA = (int*)cw;                       // alias: cw dead after phase 2
    int t = threadIdx.x, w = t >> 6, lane = t & 63;
    int bid = blockIdx.x;
    int c = (bid & (NXCD-1)) * (TOTCHK/NXCD) + (bid >> 3);   // bijective XCD swizzle
    int img = c / CHK;
    const int*   mask  = img ? mask2  : mask1;
    const float* image = img ? img2   : img1;
    const float* flow  = img ? flow2  : flow1;
    long base = (long)(c - img*CHK) * S;
    unsigned pre = 0;
    if (t < NBPI) pre = cntA[(long)c * NBPI + t];      // early global load
    for (int j = t; j < NWS*NBPI; j += 1024) ((unsigned short*)cw)[j] = 0;
    // ---- staging: 8 independent vector loads, pixel-order LDS layout ----
    {
        const int4*   mk = (const int4*)mask;
        const float4* iv = (const float4*)image;
        const float4* fx = (const float4*)flow;
        const float4* fy = (const float4*)(flow + HW);
        long i0 = (base >> 2) + (long)w*128 + lane;    // q=0 vec index
        long i1 = i0 + 64;                             // q=1
        int4   m0 = mk[i0], m1 = mk[i1];
        float4 v0 = iv[i0], v1 = iv[i1];
        float4 x0 = fx[i0], x1 = fx[i1];
        float4 y0 = fy[i0], y1 = fy[i1];
        int p0 = (w<<9) + (lane<<2);                   // within-chunk pixel idx
        ushort4 s0, s1;
        s0.x = (unsigned short)((m0.x-1) | (((x0.x<0.f?0:(x0.x==0.f?1:2))*3 + (y0.x<0.f?0:(y0.x==0.f?1:2))) << 12));
        s0.y = (unsigned short)((m0.y-1) | (((x0.y<0.f?0:(x0.y==0.f?1:2))*3 + (y0.y<0.f?0:(y0.y==0.f?1:2))) << 12));
        s0.z = (unsigned short)((m0.z-1) | (((x0.z<0.f?0:(x0.z==0.f?1:2))*3 + (y0.z<0.f?0:(y0.z==0.f?1:2))) << 12));
        s0.w = (unsigned short)((m0.w-1) | (((x0.w<0.f?0:(x0.w==0.f?1:2))*3 + (y0.w<0.f?0:(y0.w==0.f?1:2))) << 12));
        s1.x = (unsigned short)((m1.x-1) | (((x1.x<0.f?0:(x1.x==0.f?1:2))*3 + (y1.x<0.f?0:(y1.x==0.f?1:2))) << 12));
        s1.y = (unsigned short)((m1.y-1) | (((x1.y<0.f?0:(x1.y==0.f?1:2))*3 + (y1.y<0.f?0:(y1.y==0.f?1:2))) << 12));
        s1.z = (unsigned short)((m1.z-1) | (((x1.z<0.f?0:(x1.z==0.f?1:2))*3 + (y1.z<0.f?0:(y1.z==0.f?1:2))) << 12));
        s1.w = (unsigned short)((m1.w-1) | (((x1.w<0.f?0:(x1.w==0.f?1:2))*3 + (y1.w<0.f?0:(y1.w==0.f?1:2))) << 12));
        *(float4*)&ivs[p0]         = v0;
        *(float4*)&ivs[p0 + 256]   = v1;
        *(ushort4*)&smeta[p0]       = s0;
        *(ushort4*)&smeta[p0 + 256] = s1;
    }
    __syncthreads();
    // phase 1: lane-strided LDS reads (pixel order) + ballots; pack into pk
    int   pk[8];
    float piv[8];
    unsigned long long ltmask = (1ull << lane) - 1ull;
    #pragma unroll
    for (int it = 0; it < 8; ++it) {
        int p = (w<<9) + (it<<6) + lane;
        float ivx = ivs[p];
        int mt = (int)smeta[p];
        int bkt = (mt & 4095) >> 4;
        unsigned long long m = match_bits<8>(bkt);
        int cb = __popcll(m & ltmask);
        int ct = __popcll(m);
        piv[it] = ivx;
        pk[it] = (mt & 0xFFFF) | (cb << 16) | (ct << 22);
        if (cb == 0) cw[w][bkt] += (unsigned short)ct;   // leaders: distinct addrs
    }
    __syncthreads();
    // block scan over 256 buckets via wave shfl (threads 0..255 = 4 waves)
    int tot = 0, incl = 0;
    if (t < NBPI) {
        #pragma unroll
        for (int q = 0; q < NWS; ++q) tot += cw[q][t];
        incl = tot;
        #pragma unroll
        for (int off = 1; off < 64; off <<= 1) {
            int o = __shfl_up(incl, off);
            if (lane >= off) incl += o;
        }
        if (lane == 63) wsum[w] = incl;
    }
    __syncthreads();
    int gof = 0;
    if (t < NBPI) {
        int add = 0;
        for (int q = 0; q < w; ++q) add += wsum[q];
        int excl = incl + add - tot;                 // chunk-local bucket offset
        int run = excl;
        #pragma unroll
        for (int q = 0; q < NWS; ++q) {
            int cq = cw[q][t];
            cw[q][t] = (unsigned short)run;
            run += cq;
        }
        gof = (img*NBPI + t) * BTOT + (int)pre - excl;   // static bucketBase
    }
    __syncthreads();
    // phase 2: place records (register-cached, stable)
    #pragma unroll
    for (int it = 0; it < 8; ++it) {
        int pkv = pk[it];
        int l = pkv & 4095, bin = (pkv >> 12) & 15;
        int cb = (pkv >> 16) & 63, ct = (pkv >> 22) & 127;
        int bkt = l >> 4;
        int r0 = (int)cw[w][bkt];
        int dst = r0 + cb;
        if (cb == ct - 1) cw[w][bkt] = (unsigned short)(r0 + ct);
        ivs[dst] = piv[it];
        smeta[dst] = (unsigned short)((bkt << 8) | (bin << 4) | (l & 15));
    }
    __syncthreads();
    if (t < NBPI) gofsA[t] = gof;                    // cw region now dead
    __syncthreads();
    // phase 3: linear flush — consecutive j => contiguous global runs (32 recs)
    for (int j = t; j < S; j += 1024) {
        int ms = (int)smeta[j];
        int b = ms >> 8;
        int g = gofsA[b] + j;
        riv[g]   = ivs[j];
        rmeta[g] = (unsigned char)(ms & 0xFF);
    }
}

// ---- pass 4: fused rank + features; 1024 threads, 2 blocks/CU ------------
__global__ void __launch_bounds__(1024) stageB_kernel(
        const float* __restrict__ riv, const unsigned char* __restrict__ rmeta,
        float* __restrict__ out) {
    __shared__ float acc[LPB * NF];          // 12.8 KB
    __shared__ float s_tw[MAXPIX];           // 4 KB
    __shared__ int   s_tk[MAXPIX];           // 4 KB
    __shared__ int   hist[LPB * 9];          // 576 B
    __shared__ int   qc[16][LPB];            // 1 KB
    __shared__ int   cur[16][LPB];           // 1 KB
    int t = threadIdx.x, w = t >> 6, lane = t & 63;
    int gb = blockIdx.x;
    for (int j = t; j < LPB*NF; j += 1024) acc[j] = 0.f;
    if (t < MAXPIX) s_tk[t] = -1;
    if (t < LPB*9) hist[t] = 0;
    for (int j = t; j < 16*LPB; j += 1024) ((int*)qc)[j] = 0;
    __syncthreads();
    if (t < NF) {                            // static table (cnt == MAXPIX)
        const float Lf = (float)MAXPIX;
        float p = ((float)t + 0.5f) * (Lf / (float)NF) - 0.5f;
        p = fminf(fmaxf(p, 0.0f), Lf - 1.0f);
        int i0 = (int)floorf(p);
        int i1 = min(i0 + 1, MAXPIX - 1);
        float wg = p - (float)i0;
        s_tk[i0] = t; s_tw[i0] = 1.0f - wg;  // spacing 5.12 => no collision
        s_tk[i1] = t; s_tw[i1] = wg;
    }
    long base = (long)gb * BTOT;
    const int qsz = BTOT / 16;               // 1024 per wave segment (exact)
    int qbeg = w * qsz;
    const int nit = qsz / 64;                // 16
    unsigned long long ltmask = (1ull << lane) - 1ull;
    // phase 1: per-segment per-label counts — uchar4 loads + LDS atomics
    {
        const uchar4* rm4 = (const uchar4*)(rmeta + base + qbeg);
        #pragma unroll
        for (int it = 0; it < nit/4; ++it) {
            uchar4 m = rm4[it*64 + lane];
            atomicAdd(&qc[w][m.x & 15], 1);
            atomicAdd(&qc[w][m.y & 15], 1);
            atomicAdd(&qc[w][m.z & 15], 1);
            atomicAdd(&qc[w][m.w & 15], 1);
        }
    }
    __syncthreads();
    if (t < LPB) {
        int s = 0;
        #pragma unroll
        for (int q = 0; q < 16; ++q) { cur[q][t] = s; s += qc[q][t]; }
    }
    __syncthreads();
    // phase 2: stable rank + reduce (rmeta re-read is L1-hot: 16 KB/block)
    #pragma unroll 4
    for (int it = 0; it < nit; ++it) {
        int i = qbeg + it*64 + lane;
        int meta = (int)rmeta[base + i];
        float iv = riv[base + i];
        int ll = meta & 15;
        unsigned long long m = match_bits<4>(ll);
        int cb = __popcll(m & ltmask);
        int ct = __popcll(m);
        int r0 = cur[w][ll];
        int rank = r0 + cb;
        if (cb == ct - 1) cur[w][ll] = r0 + ct;
        atomicAdd(&hist[ll*9 + (meta >> 4)], 1);
        int k = s_tk[rank];
        if (k >= 0) atomicAdd(&acc[ll*NF + k], iv * s_tw[rank]);  // commutative-exact pair
    }
    __syncthreads();
    // epilogue: fully contiguous 16x209 block write
    for (int j = t; j < LPB*FEAT; j += 1024) {
        int r = j / FEAT, k = j - r*FEAT;
        float v = (k < NF) ? acc[r*NF + k] : (float)hist[r*9 + (k - NF)];
        out[(long)gb * LPB * FEAT + j] = v;
    }
}

// ---- edges: top-2 nearest centers (bbox2 x/y LDS-staged) ------------------
__device__ __forceinline__ bool better(float d, int j, float d2, int j2) {
    return d < d2 || (d == d2 && j < j2);
}

__global__ void __launch_bounds__(256) edge_kernel(const float* __restrict__ bbox1,
                                                   const float* __restrict__ bbox2,
                                                   const float* __restrict__ zfm,
                                                   float* __restrict__ out) {
    __shared__ float sbx[NI], sby[NI];       // 32 KB
    int wave = threadIdx.x >> 6, lane = threadIdx.x & 63;
    for (int r = threadIdx.x; r < NI; r += 256) {
        float4 b = ((const float4*)bbox2)[r];
        sbx[r] = b.x; sby[r] = b.y;
    }
    __syncthreads();
    int i = blockIdx.x * 4 + wave;
    float c1x = bbox1[i*4 + 0], c1y = bbox1[i*4 + 1];
    float d0 = INFINITY; int j0 = 0x7fffffff;
    float d1 = INFINITY; int j1 = 0x7fffffff;
    for (int t = 0; t < NI; t += 64) {
        int j = t + lane;
        float dx = c1x - sbx[j];
        float dy = c1y - sby[j];
        float dsq = dx*dx + dy*dy;                 // no fma (contract off)
        float d = (float)sqrt((double)dsq);        // correctly-rounded f32 sqrt
        if (better(d, j, d0, j0)) { d1 = d0; j1 = j0; d0 = d; j0 = j; }
        else if (better(d, j, d1, j1)) { d1 = d; j1 = j; }
    }
    for (int off = 32; off; off >>= 1) {
        float od0 = __shfl_down(d0, off); int oj0 = __shfl_down(j0, off);
        float od1 = __shfl_down(d1, off); int oj1 = __shfl_down(j1, off);
        if (better(od0, oj0, d0, j0)) {
            if (better(d0, j0, od1, oj1)) { d1 = d0; j1 = j0; }
            else                          { d1 = od1; j1 = oj1; }
            d0 = od0; j0 = oj0;
        } else if (better(od0, oj0, d1, j1)) { d1 = od0; j1 = oj0; }
    }
    if (lane == 0) {
        float z1 = zfm[i];
        int js[2] = { j0, j1 };
        for (int t = 0; t < 2; ++t) {
            int e = i*2 + t, j = js[t];
            out[EIOFF + e]      = (float)i;
            out[EIOFF + NE + e] = (float)(j + NI);
            float* ea = out + EAOFF + (long)e * 6;
            ea[0] = z1;
            ea[1] = zfm[NI + j];
            ea[2] = c1x - bbox2[j*4 + 0];
            ea[3] = c1y - bbox2[j*4 + 1];
            ea[4] = bbox1[i*4 + 2] / bbox2[j*4 + 2];
            ea[5] = bbox1[i*4 + 3] / bbox2[j*4 + 3];
        }
    }
}

extern "C" void kernel_launch(void* const* d_in, const int* in_sizes, int n_in,
                              void* d_out, int out_size, void* d_ws, size_t ws_size,
                              hipStream_t stream) {
    const float* img1  = (const float*)d_in[0];
    const float* img2  = (const float*)d_in[1];
    const float* flow1 = (const float*)d_in[2];
    const float* flow2 = (const float*)d_in[3];
    const float* bbox1 = (const float*)d_in[4];
    const float* bbox2 = (const float*)d_in[5];
    const int*   mask1 = (const int*)d_in[6];
    const int*   mask2 = (const int*)d_in[7];
    float* out = (float*)d_out;

    char* ws = (char*)d_ws;
    size_t off = 0;
    unsigned* cntA   = (unsigned*)(ws + off); off += (size_t)TOTCHK * NBPI * 4;  // 1 MB
    float*    riv    = (float*)(ws + off);    off += (size_t)REC * 4;            // 33.5 MB
    float*    zfpart = (float*)(ws + off);    off += (size_t)TOTCHK * NI * 4;    // 16.8 MB
    float*    zfm    = (float*)(ws + off);    off += 2 * NI * 4;
    unsigned char* rmeta = (unsigned char*)(ws + off); off += (size_t)REC;       // 8.4 MB

    hipLaunchKernelGGL(count_zf_kernel, dim3(TOTCHK), dim3(512), 0, stream,
                       mask1, mask2, flow1, flow2, cntA, zfpart);
    hipLaunchKernelGGL(scan_zf_kernel, dim3(NBG + 128), dim3(1024), 0, stream,
                       cntA, zfpart, zfm);
    hipLaunchKernelGGL(sort_kernel, dim3(TOTCHK), dim3(1024), 0, stream,
                       img1, img2, flow1, flow2, mask1, mask2, cntA, riv, rmeta);
    hipLaunchKernelGGL(stageB_kernel, dim3(NBG), dim3(1024), 0, stream,
                       riv, rmeta, out);
    hipLaunchKernelGGL(edge_kernel, dim3(NI/4), dim3(256), 0, stream,
                       bbox1, bbox2, zfm, out);
}

// Round 7
// 272.033 us; speedup vs baseline: 1.1122x; 1.1122x over previous
//
#include <hip/hip_runtime.h>
#include <math.h>

#pragma clang fp contract(off)

#define HW      (2048*2048)
#define NI      4096        // instances per image
#define MAXPIX  1024        // pixels per instance (equal partition)
#define NF      200
#define FEAT    209
#define NE      (NI*2)
#define XSIZE   ((2*NI)*FEAT)
#define EIOFF   XSIZE
#define EAOFF   (EIOFF + 2*NE)

#define S       8192        // pixels per chunk (one sort block)
#define CHK     (HW/S)      // 512 chunks per image
#define TOTCHK  (2*CHK)     // 1024
#define NBPI    256         // buckets per image (16 labels each)
#define LPB     16
#define NBG     (2*NBPI)    // 512 global buckets
#define REC     (2*HW)
#define BTOT    (LPB*MAXPIX) // 16384 records per bucket (equal partition => static)
#define NWS     16          // waves per sort block
#define NXCD    8

template<int NB>
__device__ __forceinline__ unsigned long long match_bits(int v) {
    unsigned long long m = ~0ull;
    #pragma unroll
    for (int bit = 0; bit < NB; ++bit) {
        unsigned long long bb = __ballot((v >> bit) & 1);
        m &= ((v >> bit) & 1) ? bb : ~bb;
    }
    return m;
}

// ---- pass 1: per-chunk bucket counts (mask-only) -------------------------
__global__ void __launch_bounds__(512) count_kernel(const int* __restrict__ mask1,
        const int* __restrict__ mask2, unsigned* __restrict__ cntA) {
    __shared__ unsigned cnt[8][NBPI];    // 8 KB
    int t = threadIdx.x, w = t >> 6, lane = t & 63;
    for (int j = t; j < 8*NBPI; j += 512) ((unsigned*)cnt)[j] = 0u;
    __syncthreads();
    int c = blockIdx.x;
    int img = c / CHK;
    const int4* mask = (const int4*)(img ? mask2 : mask1);
    long base4 = (long)(c - img*CHK) * (S/4) + (long)w * (S/32);  // 256 vecs/wave
    #pragma unroll
    for (int it = 0; it < S/32; it += 64) {
        int4 l4 = mask[base4 + it + lane];
        atomicAdd(&cnt[w][(l4.x-1) >> 4], 1u);
        atomicAdd(&cnt[w][(l4.y-1) >> 4], 1u);
        atomicAdd(&cnt[w][(l4.z-1) >> 4], 1u);
        atomicAdd(&cnt[w][(l4.w-1) >> 4], 1u);
    }
    __syncthreads();
    if (t < NBPI) {
        unsigned s = 0;
        #pragma unroll
        for (int q = 0; q < 8; ++q) s += cnt[q][t];
        cntA[(long)c * NBPI + t] = s;
    }
}

// ---- pass 2: per-bucket exclusive scan over 512 chunks (512 thr = CHK) ---
__global__ void __launch_bounds__(512) scan_kernel(unsigned* __restrict__ cntA) {
    __shared__ int wsum[8];
    int b = blockIdx.x;
    int img = b >> 8, lb = b & (NBPI - 1);
    int t = threadIdx.x, lane = t & 63, w = t >> 6;
    unsigned e = cntA[((long)img*CHK + t)*NBPI + lb];
    int incl = (int)e;
    #pragma unroll
    for (int off = 1; off < 64; off <<= 1) {
        int o = __shfl_up(incl, off);
        if (lane >= off) incl += o;
    }
    if (lane == 63) wsum[w] = incl;
    __syncthreads();
    int add = 0;
    for (int q = 0; q < w; ++q) add += wsum[q];
    cntA[((long)img*CHK + t)*NBPI + lb] = (unsigned)(incl + add - (int)e);
}

// ---- pass 3: LDS-staged stable bucket sort + fused fz accumulation -------
// 1024 threads, 73728 B LDS => 2 blocks/CU = 32 waves/CU.
__global__ void __launch_bounds__(1024, 8) sort_kernel(
        const float* __restrict__ img1, const float* __restrict__ img2,
        const float* __restrict__ flow1, const float* __restrict__ flow2,
        const int* __restrict__ mask1, const int* __restrict__ mask2,
        const unsigned* __restrict__ cntA,
        float* __restrict__ riv, unsigned char* __restrict__ rmeta,
        float* __restrict__ zfpart) {
    __shared__ float ivs[S];                     // 32 KB (staging, then records)
    __shared__ unsigned short smeta[S];          // 16 KB (staging, then records)
    __shared__ unsigned short cw[NWS][NBPI];     // 8 KB
    __shared__ float zfp[NI];                    // 16 KB  => 73728 B total
    int* wsum  = (int*)smeta;                    // alias: staged metas consumed first
    int* gofsA = (int*)cw;                       // alias: cw dead after phase 2
    int t = threadIdx.x, w = t >> 6, lane = t & 63;
    int bid = blockIdx.x;
    int c = (bid & (NXCD-1)) * (TOTCHK/NXCD) + (bid >> 3);   // bijective XCD swizzle
    int img = c / CHK;
    const int*   mask  = img ? mask2  : mask1;
    const float* image = img ? img2   : img1;
    const float* flow  = img ? flow2  : flow1;
    long base = (long)(c - img*CHK) * S;
    unsigned pre = 0;
    if (t < NBPI) pre = cntA[(long)c * NBPI + t];      // early global load
    for (int j = t; j < NWS*NBPI; j += 1024) ((unsigned short*)cw)[j] = 0;
    for (int j = t; j < NI; j += 1024) zfp[j] = 0.f;
    __syncthreads();                                   // zfp init before atomics
    // ---- staging: wide independent loads, pixel-order LDS layout + fz ----
    {
        const int4*   mk = (const int4*)mask;
        const float4* iv = (const float4*)image;
        const float4* fx = (const float4*)flow;
        const float4* fy = (const float4*)(flow + HW);
        const float4* fz = (const float4*)(flow + 2L*HW);
        long i0 = (base >> 2) + (long)w*128 + lane;    // q=0 vec index
        long i1 = i0 + 64;                             // q=1
        int4   m0 = mk[i0], m1 = mk[i1];
        float4 v0 = iv[i0], v1 = iv[i1];
        float4 x0 = fx[i0], x1 = fx[i1];
        float4 y0 = fy[i0], y1 = fy[i1];
        int p0 = (w<<9) + (lane<<2);                   // within-chunk pixel idx
        ushort4 s0, s1;
        s0.x = (unsigned short)((m0.x-1) | (((x0.x<0.f?0:(x0.x==0.f?1:2))*3 + (y0.x<0.f?0:(y0.x==0.f?1:2))) << 12));
        s0.y = (unsigned short)((m0.y-1) | (((x0.y<0.f?0:(x0.y==0.f?1:2))*3 + (y0.y<0.f?0:(y0.y==0.f?1:2))) << 12));
        s0.z = (unsigned short)((m0.z-1) | (((x0.z<0.f?0:(x0.z==0.f?1:2))*3 + (y0.z<0.f?0:(y0.z==0.f?1:2))) << 12));
        s0.w = (unsigned short)((m0.w-1) | (((x0.w<0.f?0:(x0.w==0.f?1:2))*3 + (y0.w<0.f?0:(y0.w==0.f?1:2))) << 12));
        s1.x = (unsigned short)((m1.x-1) | (((x1.x<0.f?0:(x1.x==0.f?1:2))*3 + (y1.x<0.f?0:(y1.x==0.f?1:2))) << 12));
        s1.y = (unsigned short)((m1.y-1) | (((x1.y<0.f?0:(x1.y==0.f?1:2))*3 + (y1.y<0.f?0:(y1.y==0.f?1:2))) << 12));
        s1.z = (unsigned short)((m1.z-1) | (((x1.z<0.f?0:(x1.z==0.f?1:2))*3 + (y1.z<0.f?0:(y1.z==0.f?1:2))) << 12));
        s1.w = (unsigned short)((m1.w-1) | (((x1.w<0.f?0:(x1.w==0.f?1:2))*3 + (y1.w<0.f?0:(y1.w==0.f?1:2))) << 12));
        *(float4*)&ivs[p0]         = v0;
        *(float4*)&ivs[p0 + 256]   = v1;
        *(ushort4*)&smeta[p0]       = s0;
        *(ushort4*)&smeta[p0 + 256] = s1;
        float4 z0 = fz[i0], z1 = fz[i1];
        atomicAdd(&zfp[m0.x-1], z0.x);
        atomicAdd(&zfp[m0.y-1], z0.y);
        atomicAdd(&zfp[m0.z-1], z0.z);
        atomicAdd(&zfp[m0.w-1], z0.w);
        atomicAdd(&zfp[m1.x-1], z1.x);
        atomicAdd(&zfp[m1.y-1], z1.y);
        atomicAdd(&zfp[m1.z-1], z1.z);
        atomicAdd(&zfp[m1.w-1], z1.w);
    }
    __syncthreads();
    // phase 1: lane-strided LDS reads (pixel order) + ballots; pack into pk
    int   pk[8];
    float piv[8];
    unsigned long long ltmask = (1ull << lane) - 1ull;
    #pragma unroll
    for (int it = 0; it < 8; ++it) {
        int p = (w<<9) + (it<<6) + lane;
        float ivx = ivs[p];
        int mt = (int)smeta[p];
        int bkt = (mt & 4095) >> 4;
        unsigned long long m = match_bits<8>(bkt);
        int cb = __popcll(m & ltmask);
        int ct = __popcll(m);
        piv[it] = ivx;
        pk[it] = (mt & 0xFFFF) | (cb << 16) | (ct << 22);
        if (cb == 0) cw[w][bkt] += (unsigned short)ct;   // leaders: distinct addrs
    }
    __syncthreads();
    // block scan over 256 buckets via wave shfl (threads 0..255 = 4 waves)
    int tot = 0, incl = 0;
    if (t < NBPI) {
        #pragma unroll
        for (int q = 0; q < NWS; ++q) tot += cw[q][t];
        incl = tot;
        #pragma unroll
        for (int off = 1; off < 64; off <<= 1) {
            int o = __shfl_up(incl, off);
            if (lane >= off) incl += o;
        }
        if (lane == 63) wsum[w] = incl;
    }
    __syncthreads();
    int gof = 0;
    if (t < NBPI) {
        int add = 0;
        for (int q = 0; q < w; ++q) add += wsum[q];
        int excl = incl + add - tot;                 // chunk-local bucket offset
        int run = excl;
        #pragma unroll
        for (int q = 0; q < NWS; ++q) {
            int cq = cw[q][t];
            cw[q][t] = (unsigned short)run;
            run += cq;
        }
        gof = (img*NBPI + t) * BTOT + (int)pre - excl;   // static bucketBase
    }
    __syncthreads();
    // phase 2: place records (register-cached, stable)
    #pragma unroll
    for (int it = 0; it < 8; ++it) {
        int pkv = pk[it];
        int l = pkv & 4095, bin = (pkv >> 12) & 15;
        int cb = (pkv >> 16) & 63, ct = (pkv >> 22) & 127;
        int bkt = l >> 4;
        int r0 = (int)cw[w][bkt];
        int dst = r0 + cb;
        if (cb == ct - 1) cw[w][bkt] = (unsigned short)(r0 + ct);
        ivs[dst] = piv[it];
        smeta[dst] = (unsigned short)((bkt << 8) | (bin << 4) | (l & 15));
    }
    __syncthreads();
    if (t < NBPI) gofsA[t] = gof;                    // cw region now dead
    __syncthreads();
    // phase 3: linear flush — consecutive j => contiguous global runs (32 recs)
    for (int j = t; j < S; j += 1024) {
        int ms = (int)smeta[j];
        int b = ms >> 8;
        int g = gofsA[b] + j;
        riv[g]   = ivs[j];
        rmeta[g] = (unsigned char)(ms & 0xFF);
    }
    // fz partials writeback (complete since the post-staging barrier)
    for (int j = t; j < NI; j += 1024) zfpart[(long)c * NI + j] = zfp[j];
}

// ---- pass 4: direct-rank features (label = i>>10, rank = i&1023) ---------
// blocks [0,NBG): features; blocks [NBG,NBG+128): zf reduction.
__global__ void __launch_bounds__(1024) stageB_kernel(
        const float* __restrict__ riv, const unsigned char* __restrict__ rmeta,
        const float* __restrict__ zfpart, float* __restrict__ out,
        float* __restrict__ zfm) {
    __shared__ float sv[4096];               // 16 KB: 4 labels of records
    __shared__ int   s_i0[NF];
    __shared__ float s_w[NF];
    __shared__ int   hist[LPB * 9];
    __shared__ float red[16][64];            // zfred branch
    int t = threadIdx.x, w = t >> 6, lane = t & 63;
    int b = blockIdx.x;
    if (b >= NBG) {
        // zf reduction: 64 labels per block, fully coalesced 256B/wave loads
        int b2 = b - NBG;                    // 0..127
        int img = b2 >> 6;
        int l0  = (b2 & 63) * 64;
        const float* p = zfpart + ((long)img*CHK + w)*NI + l0 + lane;
        float s = 0.f;
        #pragma unroll 8
        for (int r = 0; r < CHK; r += 16) s += p[(long)r*NI];
        red[w][lane] = s;
        __syncthreads();
        if (t < 64) {
            float sum = 0.f;
            #pragma unroll
            for (int g = 0; g < 16; ++g) sum += red[g][t];
            zfm[img*NI + l0 + t] = sum * (1.0f/(float)MAXPIX);   // exact /1024
        }
        return;
    }
    if (t < NF) {                            // static interp table (cnt == 1024)
        const float Lf = (float)MAXPIX;
        float p = ((float)t + 0.5f) * (Lf / (float)NF) - 0.5f;
        p = fminf(fmaxf(p, 0.0f), Lf - 1.0f);
        int i0 = (int)floorf(p);
        s_i0[t] = i0;                        // i0+1 <= 1023 always (p <= 1020.94)
        s_w[t]  = p - (float)i0;
    }
    if (t < LPB*9) hist[t] = 0;
    __syncthreads();
    long base = (long)b * BTOT;
    unsigned long long ltmask = (1ull << lane) - 1ull;
    #pragma unroll
    for (int g = 0; g < 4; ++g) {
        // stage 4 labels (4096 records) coalesced; wave covers 256 recs = 1 label
        float4 v = ((const float4*)(riv + base))[g*1024 + t];
        *(float4*)&sv[4*t] = v;
        uchar4 mm = ((const uchar4*)(rmeta + base))[g*1024 + t];
        int ll = g*4 + (w >> 2);             // this wave's label row
        int bins[4] = { mm.x >> 4, mm.y >> 4, mm.z >> 4, mm.w >> 4 };
        #pragma unroll
        for (int r = 0; r < 4; ++r) {
            unsigned long long m = match_bits<4>(bins[r]);
            if ((m & ltmask) == 0)           // leader per (bin) subset
                atomicAdd(&hist[ll*9 + bins[r]], __popcll(m));
        }
        __syncthreads();
        // features: 836 threads = 4 rows x 209; contiguous global write
        if (t < 4*FEAT) {
            int r = t / FEAT, f = t - r*FEAT;
            float v2;
            if (f < NF) {
                int i0 = s_i0[f]; float wg = s_w[f];
                v2 = sv[r*1024 + i0] * (1.0f - wg) + sv[r*1024 + i0 + 1] * wg;
            } else {
                v2 = (float)hist[(g*4 + r)*9 + (f - NF)];
            }
            out[((long)b*LPB + g*4)*FEAT + t] = v2;
        }
        __syncthreads();                     // sv reuse next group
    }
}

// ---- edges: top-2 nearest centers (bbox2 x/y LDS-staged) ------------------
__device__ __forceinline__ bool better(float d, int j, float d2, int j2) {
    return d < d2 || (d == d2 && j < j2);
}

__global__ void __launch_bounds__(256) edge_kernel(const float* __restrict__ bbox1,
                                                   const float* __restrict__ bbox2,
                                                   const float* __restrict__ zfm,
                                                   float* __restrict__ out) {
    __shared__ float sbx[NI], sby[NI];       // 32 KB
    int wave = threadIdx.x >> 6, lane = threadIdx.x & 63;
    for (int r = threadIdx.x; r < NI; r += 256) {
        float4 b = ((const float4*)bbox2)[r];
        sbx[r] = b.x; sby[r] = b.y;
    }
    __syncthreads();
    int i = blockIdx.x * 4 + wave;
    float c1x = bbox1[i*4 + 0], c1y = bbox1[i*4 + 1];
    float d0 = INFINITY; int j0 = 0x7fffffff;
    float d1 = INFINITY; int j1 = 0x7fffffff;
    for (int t = 0; t < NI; t += 64) {
        int j = t + lane;
        float dx = c1x - sbx[j];
        float dy = c1y - sby[j];
        float dsq = dx*dx + dy*dy;                 // no fma (contract off)
        float d = (float)sqrt((double)dsq);        // correctly-rounded f32 sqrt
        if (better(d, j, d0, j0)) { d1 = d0; j1 = j0; d0 = d; j0 = j; }
        else if (better(d, j, d1, j1)) { d1 = d; j1 = j; }
    }
    for (int off = 32; off; off >>= 1) {
        float od0 = __shfl_down(d0, off); int oj0 = __shfl_down(j0, off);
        float od1 = __shfl_down(d1, off); int oj1 = __shfl_down(j1, off);
        if (better(od0, oj0, d0, j0)) {
            if (better(d0, j0, od1, oj1)) { d1 = d0; j1 = j0; }
            else                          { d1 = od1; j1 = oj1; }
            d0 = od0; j0 = oj0;
        } else if (better(od0, oj0, d1, j1)) { d1 = od0; j1 = oj0; }
    }
    if (lane == 0) {
        float z1 = zfm[i];
        int js[2] = { j0, j1 };
        for (int t = 0; t < 2; ++t) {
            int e = i*2 + t, j = js[t];
            out[EIOFF + e]      = (float)i;
            out[EIOFF + NE + e] = (float)(j + NI);
            float* ea = out + EAOFF + (long)e * 6;
            ea[0] = z1;
            ea[1] = zfm[NI + j];
            ea[2] = c1x - bbox2[j*4 + 0];
            ea[3] = c1y - bbox2[j*4 + 1];
            ea[4] = bbox1[i*4 + 2] / bbox2[j*4 + 2];
            ea[5] = bbox1[i*4 + 3] / bbox2[j*4 + 3];
        }
    }
}

extern "C" void kernel_launch(void* const* d_in, const int* in_sizes, int n_in,
                              void* d_out, int out_size, void* d_ws, size_t ws_size,
                              hipStream_t stream) {
    const float* img1  = (const float*)d_in[0];
    const float* img2  = (const float*)d_in[1];
    const float* flow1 = (const float*)d_in[2];
    const float* flow2 = (const float*)d_in[3];
    const float* bbox1 = (const float*)d_in[4];
    const float* bbox2 = (const float*)d_in[5];
    const int*   mask1 = (const int*)d_in[6];
    const int*   mask2 = (const int*)d_in[7];
    float* out = (float*)d_out;

    char* ws = (char*)d_ws;
    size_t off = 0;
    unsigned* cntA   = (unsigned*)(ws + off); off += (size_t)TOTCHK * NBPI * 4;  // 1 MB
    float*    riv    = (float*)(ws + off);    off += (size_t)REC * 4;            // 33.5 MB
    float*    zfpart = (float*)(ws + off);    off += (size_t)TOTCHK * NI * 4;    // 16.8 MB
    float*    zfm    = (float*)(ws + off);    off += 2 * NI * 4;
    unsigned char* rmeta = (unsigned char*)(ws + off); off += (size_t)REC;       // 8.4 MB

    hipLaunchKernelGGL(count_kernel, dim3(TOTCHK), dim3(512), 0, stream,
                       mask1, mask2, cntA);
    hipLaunchKernelGGL(scan_kernel, dim3(NBG), dim3(512), 0, stream, cntA);
    hipLaunchKernelGGL(sort_kernel, dim3(TOTCHK), dim3(1024), 0, stream,
                       img1, img2, flow1, flow2, mask1, mask2, cntA,
                       riv, rmeta, zfpart);
    hipLaunchKernelGGL(stageB_kernel, dim3(NBG + 128), dim3(1024), 0, stream,
                       riv, rmeta, zfpart, out, zfm);
    hipLaunchKernelGGL(edge_kernel, dim3(NI/4), dim3(256), 0, stream,
                       bbox1, bbox2, zfm, out);
}